// Round 1
// baseline (115.103 us; speedup 1.0000x reference)
//
#include <hip/hip_runtime.h>

// DAREController route(is_visual=True, training=True)
// B=256 rows, S=32768 tokens. One block per row.
//
// R7 -> R8: exact 3-level radix select, no candidate array, no serial finisher.
//  - Level 0: 2048-bin histogram on key bits [31:21], 4 bank-staggered copies
//    (wid&3) to cut same-address atomic serialization ~4x on the clustered
//    N(0,1) exponent distribution.
//  - Level 1: 2048-bin histogram on bits [20:10] over keys in bucket b0
//    (~600 elements/block -> negligible atomics), all 1024 threads.
//  - Level 2: 1024-bin histogram on bits [9:0] over keys matching (b0,b1)
//    (~1-2 elements/block). Threshold is then EXACT: (b0<<21)|(b1<<10)|b2.
//  - One uniform nontemporal store pass with the exact threshold replaces the
//    early/deferred split; stats accumulated in the same pass.
//  - LDS 139 KB -> ~45 KB; the 21-iteration wave-0 ballot loop (15 waves idle)
//    is replaced by ~0.5 us of parallel scans.

#define NB 256
#define NS 32768
#define KAPPA 64
#define NT 1024
#define V4 (NS / NT / 4)      // 8 vec4 per thread
#define NCOPY 4               // level-0 histogram copies
#define NBIN0 2048            // key bits [31:21]
#define PAD0 8                // stagger copies by 8 banks
#define NBIN1 2048            // key bits [20:10]
#define NBIN2 1024            // key bits [9:0]
#define NSEG 256              // scan threads

typedef float f32x4 __attribute__((ext_vector_type(4)));
typedef int   i32x4 __attribute__((ext_vector_type(4)));

__device__ __forceinline__ unsigned int fkey(float f) {
    unsigned int u = __float_as_uint(f);
    return (u & 0x80000000u) ? ~u : (u | 0x80000000u);  // monotone: bigger float -> bigger key
}

__device__ __forceinline__ float unkey(unsigned int k) {
    unsigned int u = (k & 0x80000000u) ? (k ^ 0x80000000u) : ~k;
    return __uint_as_float(u);
}

// Descending (k-th largest) crossing-bin search over NSEG segments x SEGW bins.
// Caller supplies per-thread bin counts r[] and their sum hsum (tid<NSEG only),
// plus rem (k-th from the top). Writes *out_bin / *out_rem in the crossing
// thread. Contains ONE internal barrier; caller must barrier after.
template <int SEGW>
__device__ __forceinline__ void scan_find(const unsigned int (&r)[SEGW], unsigned int hsum,
                                          unsigned int rem, unsigned int* wtot,
                                          unsigned int* out_bin, unsigned int* out_rem,
                                          const int tid, const int lane, const int wid) {
    unsigned int s = 0;
    if (tid < NSEG) {
        s = hsum;
        #pragma unroll
        for (int off = 1; off < 64; off <<= 1) {       // suffix-sum within wave
            const unsigned int t = __shfl_down(s, off);
            if (lane + off < 64) s += t;
        }
        if (lane == 0) wtot[wid] = s;
    }
    __syncthreads();                                   // wtot ready
    if (tid < NSEG) {
        unsigned int sfull = s;
        for (int w = wid + 1; w < 4; w++) sfull += wtot[w];
        const unsigned int above = sfull - hsum;       // count in higher segments
        if (sfull >= rem && above < rem) {             // crossing segment
            unsigned int cum = above;
            #pragma unroll
            for (int b = SEGW - 1; b >= 0; b--) {
                if (cum + r[b] >= rem) { *out_bin = (unsigned int)(tid * SEGW + b); *out_rem = rem - cum; break; }
                cum += r[b];
            }
        }
    }
}

__global__ __launch_bounds__(NT) void dare_rows(const float* __restrict__ imp,
                                                const int* __restrict__ mask,
                                                float* __restrict__ keep,
                                                float* __restrict__ stats) {
    __shared__ unsigned int hist0[NCOPY][NBIN0 + PAD0];  // ~32.1 KB
    __shared__ unsigned int hist1[NBIN1];                // 8 KB
    __shared__ unsigned int hist2[NBIN2];                // 4 KB
    __shared__ unsigned int wtot[4];
    __shared__ unsigned int sh_mm, sh_eff;
    __shared__ unsigned int sh_b0, sh_rem0, sh_b1, sh_rem1, sh_thresh;
    __shared__ unsigned int sh_kept, sh_ndrop;
    __shared__ float sh_dsum;

    const int row = blockIdx.x;
    const int tid = threadIdx.x;
    const int lane = tid & 63;
    const int wid = tid >> 6;
    const f32x4* rimp4  = (const f32x4*)(imp  + (size_t)row * NS);
    const i32x4* rmask4 = (const i32x4*)(mask + (size_t)row * NS);
    f32x4*       rkeep4 = (f32x4*)      (keep + (size_t)row * NS);

    #pragma unroll
    for (int c = 0; c < NCOPY; c++) { hist0[c][tid] = 0; hist0[c][tid + NT] = 0; }
    hist1[tid] = 0; hist1[tid + NT] = 0;
    hist2[tid] = 0;
    if (tid == 0) {
        sh_mm = 0; sh_eff = 0;
        sh_b0 = 0; sh_rem0 = 1; sh_b1 = 0; sh_rem1 = 1; sh_thresh = 0;
        sh_kept = 0; sh_ndrop = 0; sh_dsum = 0.0f;
    }
    __syncthreads();   // B1

    // ---- Phase 1: one streaming read -> keys in regs + level-0 histogram ----
    unsigned int keys[V4 * 4];
    unsigned int effbits = 0, mmbits = 0;
    const int hc = wid & (NCOPY - 1);

    #pragma unroll
    for (int i = 0; i < V4; i++) {
        const int idx4 = tid + i * NT;
        const f32x4 v = __builtin_nontemporal_load(&rimp4[idx4]);
        const i32x4 m = __builtin_nontemporal_load(&rmask4[idx4]);
        #pragma unroll
        for (int j = 0; j < 4; j++) {
            const int e = i * 4 + j;
            const int col = idx4 * 4 + j;
            keys[e] = fkey(v[j]);
            const bool mm  = (m[j] != 0);
            const bool eff = mm && (col >= KAPPA);
            mmbits  |= (mm  ? 1u : 0u) << e;
            effbits |= (eff ? 1u : 0u) << e;
        }
    }
    #pragma unroll
    for (int e = 0; e < V4 * 4; e++) {
        if ((effbits >> e) & 1u) atomicAdd(&hist0[hc][keys[e] >> 21], 1u);
    }

    int mm_local  = __popc(mmbits);
    int eff_local = __popc(effbits);
    #pragma unroll
    for (int off = 32; off; off >>= 1) {
        mm_local  += __shfl_down(mm_local, off);
        eff_local += __shfl_down(eff_local, off);
    }
    if (lane == 0) {
        atomicAdd(&sh_mm,  (unsigned int)mm_local);
        atomicAdd(&sh_eff, (unsigned int)eff_local);
    }
    __syncthreads();   // B2 (hist0 + counts ready)

    // ---- Level 0 scan: bits [31:21] ----
    {
        unsigned int r0[NBIN0 / NSEG] = {};
        unsigned int hsum = 0;
        if (tid < NSEG) {
            #pragma unroll
            for (int b = 0; b < NBIN0 / NSEG; b++) {
                unsigned int v = 0;
                #pragma unroll
                for (int c = 0; c < NCOPY; c++) v += hist0[c][tid * (NBIN0 / NSEG) + b];
                r0[b] = v; hsum += v;
            }
        }
        const float target = fmaxf((float)sh_mm * 0.5f, 1.0f);
        const int k = min((int)target, (int)sh_eff);
        const unsigned int rem = (unsigned int)max(k, 1);
        scan_find<NBIN0 / NSEG>(r0, hsum, rem, wtot, &sh_b0, &sh_rem0, tid, lane, wid);  // B3 inside
    }
    __syncthreads();   // B4 (b0, rem0 ready)

    // ---- Level 1: bits [20:10] over bucket-b0 keys (~600/block) ----
    const unsigned int b0 = sh_b0;
    #pragma unroll
    for (int e = 0; e < V4 * 4; e++) {
        if (((effbits >> e) & 1u) && (keys[e] >> 21) == b0)
            atomicAdd(&hist1[(keys[e] >> 10) & (NBIN1 - 1)], 1u);
    }
    __syncthreads();   // B5 (hist1 ready)
    {
        unsigned int r1[NBIN1 / NSEG] = {};
        unsigned int hsum = 0;
        if (tid < NSEG) {
            #pragma unroll
            for (int b = 0; b < NBIN1 / NSEG; b++) {
                const unsigned int v = hist1[tid * (NBIN1 / NSEG) + b];
                r1[b] = v; hsum += v;
            }
        }
        scan_find<NBIN1 / NSEG>(r1, hsum, sh_rem0, wtot, &sh_b1, &sh_rem1, tid, lane, wid);  // B6 inside
    }
    __syncthreads();   // B7 (b1, rem1 ready)

    // ---- Level 2: bits [9:0] over (b0,b1) keys (~1-2/block) ----
    const unsigned int b1 = sh_b1;
    const unsigned int top22 = (b0 << 11) | b1;
    #pragma unroll
    for (int e = 0; e < V4 * 4; e++) {
        if (((effbits >> e) & 1u) && (keys[e] >> 10) == top22)
            atomicAdd(&hist2[keys[e] & (NBIN2 - 1)], 1u);
    }
    __syncthreads();   // B8 (hist2 ready)
    {
        unsigned int r2[NBIN2 / NSEG] = {};
        unsigned int hsum = 0;
        if (tid < NSEG) {
            #pragma unroll
            for (int b = 0; b < NBIN2 / NSEG; b++) {
                const unsigned int v = hist2[tid * (NBIN2 / NSEG) + b];
                r2[b] = v; hsum += v;
            }
        }
        unsigned int dummy_rem;
        scan_find<NBIN2 / NSEG>(r2, hsum, sh_rem1, wtot, &sh_thresh, &dummy_rem, tid, lane, wid);  // B9 inside
    }
    __syncthreads();   // B10 (low-10 bin ready)

    // ---- Single uniform store pass with exact threshold ----
    const unsigned int thresh = (top22 << 10) | sh_thresh;
    const bool kpos = (sh_eff > 0);

    int kept_l = 0, ndrop_l = 0;
    float dsum_l = 0.0f;

    #pragma unroll
    for (int i = 0; i < V4; i++) {
        const int idx4 = tid + i * NT;
        f32x4 o;
        #pragma unroll
        for (int j = 0; j < 4; j++) {
            const int e = i * 4 + j;
            const int col = idx4 * 4 + j;
            const bool mm  = (mmbits >> e) & 1u;
            const bool eff = (effbits >> e) & 1u;
            const bool hard = kpos && eff && (keys[e] >= thresh);
            const bool kp = (col < KAPPA) || hard;
            o[j] = kp ? 1.0f : 0.0f;
            kept_l += (kp && mm) ? 1 : 0;
            const bool drop = mm && !kp;
            ndrop_l += drop ? 1 : 0;
            dsum_l += drop ? unkey(keys[e]) : 0.0f;
        }
        __builtin_nontemporal_store(o, &rkeep4[idx4]);
    }

    #pragma unroll
    for (int off = 32; off; off >>= 1) {
        kept_l  += __shfl_down(kept_l, off);
        ndrop_l += __shfl_down(ndrop_l, off);
        dsum_l  += __shfl_down(dsum_l, off);
    }
    if (lane == 0) {
        atomicAdd(&sh_kept,  (unsigned int)kept_l);
        atomicAdd(&sh_ndrop, (unsigned int)ndrop_l);
        atomicAdd(&sh_dsum,  dsum_l);
    }
    __syncthreads();   // B11
    if (tid == 0) {
        stats[row * 4 + 0] = (float)sh_kept;
        stats[row * 4 + 1] = (float)sh_mm;
        stats[row * 4 + 2] = (float)sh_ndrop;
        stats[row * 4 + 3] = sh_dsum;
    }
}

__global__ __launch_bounds__(256) void dare_losses(const float* __restrict__ stats,
                                                   float* __restrict__ out) {
    __shared__ float w_a[4], w_h[4], w_n[4], w_d[4];
    const int tid = threadIdx.x;   // one thread per row
    const float kept = stats[tid * 4 + 0];
    const float mmc  = stats[tid * 4 + 1];
    const float nd   = stats[tid * 4 + 2];
    const float ds   = stats[tid * 4 + 3];
    const float ratio = kept / (mmc + 1e-6f);
    float a = fabsf(ratio - 0.5f);          // |ratio - rho|
    float h = fmaxf(0.5f - ratio, 0.0f);    // relu(rho - ratio)
    float n = nd, d = ds;
    #pragma unroll
    for (int off = 32; off; off >>= 1) {
        a += __shfl_down(a, off);
        h += __shfl_down(h, off);
        n += __shfl_down(n, off);
        d += __shfl_down(d, off);
    }
    const int wid = tid >> 6, lane = tid & 63;
    if (lane == 0) { w_a[wid] = a; w_h[wid] = h; w_n[wid] = n; w_d[wid] = d; }
    __syncthreads();
    if (tid == 0) {
        float sa = 0.f, shh = 0.f, sn = 0.f, sd = 0.f;
        for (int w = 0; w < 4; w++) { sa += w_a[w]; shh += w_h[w]; sn += w_n[w]; sd += w_d[w]; }
        out[0] = sa / (float)NB;                                        // 1.0 * loss_ratio
        out[1] = (sn > 0.0f) ? 0.1f * (sd / fmaxf(sn, 1.0f)) : 0.0f;    // 0.1 * loss_soft
        out[2] = shh / (float)NB;                                       // 1.0 * loss_hard
    }
}

extern "C" void kernel_launch(void* const* d_in, const int* in_sizes, int n_in,
                              void* d_out, int out_size, void* d_ws, size_t ws_size,
                              hipStream_t stream) {
    const float* imp  = (const float*)d_in[0];
    const int*   mask = (const int*)d_in[1];
    float* out   = (float*)d_out;
    float* stats = (float*)d_ws;   // 256 rows * 4 floats = 4 KB

    dare_rows<<<NB, NT, 0, stream>>>(imp, mask, out, stats);
    dare_losses<<<1, 256, 0, stream>>>(stats, out + (size_t)NB * NS);
}